// Round 5
// baseline (390.300 us; speedup 1.0000x reference)
//
#include <hip/hip_runtime.h>
#include <math.h>

#define BB 16
#define HH 512
#define WW 512
#define HWP (HH*WW)
#define NPIX (BB*HWP)
#define HWP4 (HWP/4)
#define NG (NPIX/4)      // number of 4-pixel groups
#define NCORN 500
#define NSLOT 4096       // 64x64 tiles of 8x8 per image
#define OCAP 1024        // overflow for exact ties with block max (rare)
#define NKEY (NSLOT+OCAP)
#define NBL 4096         // k_loss blocks (= NG/256)

__device__ __constant__ float G7c[7] = {
    0.0044330482f, 0.0540055826f, 0.2420362294f, 0.3990502793f,
    0.2420362294f, 0.0540055826f, 0.0044330482f};

__device__ __forceinline__ int reflect_idx(int i, int n) {
    if (i < 0) i = -i;
    if (i >= n) i = 2 * n - 2 - i;
    return i;
}

// 1D scatter weight for reflect-padded 7-tap gaussian blur:
// contribution of source p to output o (both in [0,n)).
__device__ __forceinline__ float w1d(int p, int o, int n) {
    float w = 0.f;
    int d = p - o;
    if (d >= -3 && d <= 3) w += G7c[d + 3];
    if (p >= 1 && p + o <= 3) w += G7c[3 - p - o];              // low mirror
    if (p <= n - 2 && p + o >= 2 * n - 5) w += G7c[2 * n + 1 - p - o]; // high mirror
    return w;
}

// 1) gray = 0.299 R + 0.587 G + 0.114 B  (float4)
__global__ void k_gray(const float* __restrict__ imgs, float* __restrict__ gray) {
    int g = blockIdx.x * blockDim.x + threadIdx.x;
    if (g >= NG) return;
    int b = g / HWP4, r = g % HWP4;
    const float4* base = (const float4*)(imgs + (size_t)b * 3 * HWP);
    float4 R = base[r], G = base[r + HWP4], Bc = base[r + 2 * HWP4];
    float4 o;
    o.x = 0.299f * R.x + 0.587f * G.x + 0.114f * Bc.x;
    o.y = 0.299f * R.y + 0.587f * G.y + 0.114f * Bc.y;
    o.z = 0.299f * R.z + 0.587f * G.z + 0.114f * Bc.z;
    o.w = 0.299f * R.w + 0.587f * G.w + 0.114f * Bc.w;
    ((float4*)gray)[g] = o;
}

// 2) fused sobel (replicate) + horizontal 7-tap gaussian (reflect) of products
__global__ void k_gradH(const float* __restrict__ gray,
                        float* __restrict__ ha, float* __restrict__ hc,
                        float* __restrict__ hd) {
    int g = blockIdx.x * blockDim.x + threadIdx.x;
    if (g >= NG) return;
    int b = g / HWP4, rem = g % HWP4;
    int p = rem * 4, y = p >> 9, x0 = p & 511;
    const float* gb = gray + (size_t)b * HWP;
    int ym = max(y - 1, 0), yp = min(y + 1, HH - 1);
    const float* rm = gb + (size_t)ym * WW;
    const float* rc = gb + (size_t)y * WW;
    const float* rp = gb + (size_t)yp * WW;
    if (x0 >= 4 && x0 <= 504) {
        float r0[12], r1[12], r2[12];
        const float4* q0 = (const float4*)(rm + x0 - 4);
        const float4* q1 = (const float4*)(rc + x0 - 4);
        const float4* q2 = (const float4*)(rp + x0 - 4);
#pragma unroll
        for (int t = 0; t < 3; ++t) {
            float4 a = q0[t], bq = q1[t], c = q2[t];
            r0[4*t]=a.x; r0[4*t+1]=a.y; r0[4*t+2]=a.z; r0[4*t+3]=a.w;
            r1[4*t]=bq.x; r1[4*t+1]=bq.y; r1[4*t+2]=bq.z; r1[4*t+3]=bq.w;
            r2[4*t]=c.x; r2[4*t+1]=c.y; r2[4*t+2]=c.z; r2[4*t+3]=c.w;
        }
        float dxv[10], dyv[10];
#pragma unroll
        for (int w = 1; w <= 10; ++w) {
            float dx = (r0[w+1]-r0[w-1] + 2.f*(r1[w+1]-r1[w-1]) + r2[w+1]-r2[w-1]) * 0.125f;
            float dy = (r2[w-1]-r0[w-1] + 2.f*(r2[w]-r0[w]) + r2[w+1]-r0[w+1]) * 0.125f;
            dxv[w-1] = dx; dyv[w-1] = dy;
        }
        float4 av, cv, dv;
        float* pa = (float*)&av; float* pc = (float*)&cv; float* pd = (float*)&dv;
#pragma unroll
        for (int k = 0; k < 4; ++k) {
            float a = 0.f, c = 0.f, d = 0.f;
#pragma unroll
            for (int t = -3; t <= 3; ++t) {
                int wi = k + 3 + t;
                float w = G7c[t + 3];
                a += w * dxv[wi] * dxv[wi];
                c += w * dyv[wi] * dyv[wi];
                d += w * dxv[wi] * dyv[wi];
            }
            pa[k] = a; pc[k] = c; pd[k] = d;
        }
        ((float4*)ha)[g] = av;
        ((float4*)hc)[g] = cv;
        ((float4*)hd)[g] = dv;
    } else {
        for (int k = 0; k < 4; ++k) {
            int x = x0 + k;
            float a = 0.f, c = 0.f, d = 0.f;
            for (int t = -3; t <= 3; ++t) {
                int xx = reflect_idx(x + t, WW);
                int xm = max(xx - 1, 0), xp = min(xx + 1, WW - 1);
                float g00 = rm[xm], g01 = rm[xx], g02 = rm[xp];
                float g10 = rc[xm],               g12 = rc[xp];
                float g20 = rp[xm], g21 = rp[xx], g22 = rp[xp];
                float dx = (g02 - g00 + 2.f * (g12 - g10) + g22 - g20) * 0.125f;
                float dy = (g20 - g00 + 2.f * (g21 - g01) + g22 - g02) * 0.125f;
                float w = G7c[t + 3];
                a += w * dx * dx; c += w * dy * dy; d += w * dx * dy;
            }
            size_t i = (size_t)b * HWP + p + k;
            ha[i] = a; hc[i] = c; hd[i] = d;
        }
    }
}

// 3) vertical 7-tap gaussian (reflect) + min-eigenvalue  (float4)
__global__ void k_gfttV(const float* __restrict__ ha, const float* __restrict__ hc,
                        const float* __restrict__ hd, float* __restrict__ S) {
    int g = blockIdx.x * blockDim.x + threadIdx.x;
    if (g >= NG) return;
    int b = g / HWP4, rem = g % HWP4;
    int p = rem * 4, y = p >> 9, x0 = p & 511;
    float4 a = {0,0,0,0}, c = {0,0,0,0}, d = {0,0,0,0};
#pragma unroll
    for (int j = -3; j <= 3; ++j) {
        int yy = reflect_idx(y + j, HH);
        float w = G7c[j + 3];
        size_t i4 = ((size_t)b * HWP + (size_t)yy * WW + x0) >> 2;
        float4 qa = ((const float4*)ha)[i4];
        float4 qc = ((const float4*)hc)[i4];
        float4 qd = ((const float4*)hd)[i4];
        a.x += w*qa.x; a.y += w*qa.y; a.z += w*qa.z; a.w += w*qa.w;
        c.x += w*qc.x; c.y += w*qc.y; c.z += w*qc.z; c.w += w*qc.w;
        d.x += w*qd.x; d.y += w*qd.y; d.z += w*qd.z; d.w += w*qd.w;
    }
    float4 o;
    float* pa = (float*)&a; float* pc = (float*)&c; float* pd = (float*)&d; float* po = (float*)&o;
#pragma unroll
    for (int k = 0; k < 4; ++k) {
        float det = pa[k] * pc[k] - pd[k] * pd[k];
        float tr = pa[k] + pc[k];
        po[k] = 0.5f * (tr - sqrtf(fabsf(tr * tr - 4.f * det)));
    }
    ((float4*)S)[g] = o;
}

// 4a) horizontal 5-wide max (in-bounds)  (float4)
__global__ void k_nms1h(const float* __restrict__ S, float* __restrict__ hm) {
    int g = blockIdx.x * blockDim.x + threadIdx.x;
    if (g >= NG) return;
    int b = g / HWP4, rem = g % HWP4;
    int p = rem * 4, x0 = p & 511;
    const float* row = S + (size_t)b * HWP + (p - x0);
    if (x0 >= 4 && x0 <= 504) {
        float f[12];
        const float4* q = (const float4*)(row + x0 - 4);
#pragma unroll
        for (int t = 0; t < 3; ++t) {
            float4 v = q[t];
            f[4*t]=v.x; f[4*t+1]=v.y; f[4*t+2]=v.z; f[4*t+3]=v.w;
        }
        float4 o; float* po = (float*)&o;
#pragma unroll
        for (int k = 0; k < 4; ++k) {
            float m = f[k+2];
            m = fmaxf(m, f[k+3]); m = fmaxf(m, f[k+4]);
            m = fmaxf(m, f[k+5]); m = fmaxf(m, f[k+6]);
            po[k] = m;
        }
        ((float4*)hm)[g] = o;
    } else {
        for (int k = 0; k < 4; ++k) {
            int x = x0 + k;
            int xa = max(x - 2, 0), xb = min(x + 2, WW - 1);
            float m = -INFINITY;
            for (int xx = xa; xx <= xb; ++xx) m = fmaxf(m, row[xx]);
            hm[(size_t)b * HWP + p + k] = m;
        }
    }
}

// 5) fused vertical NMS + per-8x8-tile max -> fixed slot; ties overflow
__global__ void k_cand(const float* __restrict__ hm, const float* __restrict__ S,
                       float* __restrict__ sval, int* __restrict__ sidx,
                       int* __restrict__ ocnt) {
    int wave = threadIdx.x >> 6, lane = threadIdx.x & 63;
    int tx = blockIdx.x * 4 + wave;      // tile col 0..63
    int ty = blockIdx.y;                 // tile row 0..63
    int b = blockIdx.z;
    int ly = lane >> 3, lx = lane & 7;
    int y = ty * 8 + ly, x = tx * 8 + lx;
    const float* hb = hm + (size_t)b * HWP;
    int y0 = max(y - 2, 0), y1 = min(y + 2, HH - 1);
    float m = -INFINITY;
    for (int yy = y0; yy <= y1; ++yy) m = fmaxf(m, hb[yy * WW + x]);
    float v = S[(size_t)b * HWP + y * WW + x];
    float cval = (v == m) ? v : 0.f;      // NMS result
    float tm = cval;
#pragma unroll
    for (int off = 32; off; off >>= 1)
        tm = fmaxf(tm, __shfl_xor(tm, off));
    unsigned long long mask = __ballot(cval == tm && cval > 0.f);
    int slot = ty * 64 + tx;
    if (mask) {
        int first = __ffsll(mask) - 1;
        if (lane == first) {
            sval[b * NKEY + slot] = cval;
            sidx[b * NKEY + slot] = y * WW + x;
        } else if ((mask >> lane) & 1ull) {
            int pos = atomicAdd(&ocnt[b], 1);
            if (pos < OCAP) {
                sval[b * NKEY + NSLOT + pos] = cval;
                sidx[b * NKEY + NSLOT + pos] = y * WW + x;
            }
        }
    } else if (lane == 0) {
        sval[b * NKEY + slot] = 0.f;
        sidx[b * NKEY + slot] = 0;
    }
}

// 6) exact 500th-largest key per image via 8x8-bit radix select (keys unique)
__global__ void k_sel1(const float* __restrict__ sval, const int* __restrict__ sidx,
                       const int* __restrict__ ocnt, unsigned long long* __restrict__ selK) {
    __shared__ unsigned long long keys[NKEY];
    __shared__ unsigned int hist[256];
    __shared__ unsigned int sh_cnt;
    __shared__ unsigned long long sh_prefix;
    __shared__ int sh_rem;
    int b = blockIdx.x;
    int n = NSLOT + min(ocnt[b], OCAP);
    if (threadIdx.x == 0) sh_cnt = 0;
    __syncthreads();
    unsigned int cnt = 0;
    for (int i = threadIdx.x; i < n; i += blockDim.x) {
        float v = sval[b * NKEY + i];
        unsigned long long k = 0ull;
        if (v > 0.f) {
            unsigned int ix = (unsigned int)sidx[b * NKEY + i];
            k = ((unsigned long long)__float_as_uint(v) << 32) | (unsigned int)(~ix);
            cnt++;
        }
        keys[i] = k;
    }
    atomicAdd(&sh_cnt, cnt);
    __syncthreads();
    int target = min(NCORN, (int)sh_cnt);
    if (target == 0) { if (threadIdx.x == 0) selK[b] = ~0ull; return; }
    unsigned long long prefix = 0ull;
    int remaining = target;
    for (int shift = 56; shift >= 0; shift -= 8) {
        for (int i = threadIdx.x; i < 256; i += blockDim.x) hist[i] = 0;
        __syncthreads();
        unsigned long long himask = (shift + 8 < 64) ? (~0ull << (shift + 8)) : 0ull;
        for (int i = threadIdx.x; i < n; i += blockDim.x) {
            unsigned long long k = keys[i];
            if (k && ((k ^ prefix) & himask) == 0ull)
                atomicAdd(&hist[(unsigned int)(k >> shift) & 0xffu], 1u);
        }
        __syncthreads();
        if (threadIdx.x == 0) {
            int rem = remaining, bin = 255;
            for (; bin > 0; --bin) {
                int c = (int)hist[bin];
                if (rem - c <= 0) break;
                rem -= c;
            }
            sh_prefix = prefix | ((unsigned long long)(unsigned int)bin << shift);
            sh_rem = rem;
        }
        __syncthreads();
        prefix = sh_prefix;
        remaining = sh_rem;
        __syncthreads();
    }
    if (threadIdx.x == 0) selK[b] = prefix;
}

// 7) scatter selected candidates into target image
__global__ void k_scat(const float* __restrict__ sval, const int* __restrict__ sidx,
                       const int* __restrict__ ocnt, const unsigned long long* __restrict__ selK,
                       float* __restrict__ target) {
    int gid = blockIdx.x * blockDim.x + threadIdx.x;
    if (gid >= BB * NKEY) return;
    int b = gid / NKEY, s = gid % NKEY;
    if (s >= NSLOT + min(ocnt[b], OCAP)) return;
    float v = sval[gid];
    if (v <= 0.f) return;
    unsigned int ix = (unsigned int)sidx[gid];
    unsigned long long k = ((unsigned long long)__float_as_uint(v) << 32) | (unsigned int)(~ix);
    if (k >= selK[b])
        target[(size_t)b * HWP + ix] = v;
}

// 8) sparse NMS on scattered points + direct gaussian stamp into corners
__global__ void k_post(const float* __restrict__ sval, const int* __restrict__ sidx,
                       const int* __restrict__ ocnt, const unsigned long long* __restrict__ selK,
                       const float* __restrict__ target, float* __restrict__ corners) {
    int gid = blockIdx.x * blockDim.x + threadIdx.x;
    if (gid >= BB * NKEY) return;
    int b = gid / NKEY, s = gid % NKEY;
    if (s >= NSLOT + min(ocnt[b], OCAP)) return;
    float v = sval[gid];
    if (v <= 0.f) return;
    unsigned int ix = (unsigned int)sidx[gid];
    unsigned long long k = ((unsigned long long)__float_as_uint(v) << 32) | (unsigned int)(~ix);
    if (k < selK[b]) return;
    int y = (int)(ix >> 9), x = (int)(ix & 511);
    const float* tb = target + (size_t)b * HWP;
    // in-bounds 5x5 window max (second NMS)
    int ya = max(y - 2, 0), yb = min(y + 2, HH - 1);
    int xa = max(x - 2, 0), xb = min(x + 2, WW - 1);
    float m = -INFINITY;
    for (int yy = ya; yy <= yb; ++yy)
        for (int xx = xa; xx <= xb; ++xx)
            m = fmaxf(m, tb[yy * WW + xx]);
    if (v != m) return;   // suppressed
    // stamp 7x7 reflect-pad gaussian of a unit impulse at (y,x)
    float* cb = corners + (size_t)b * HWP;
    if (y >= 3 && y <= HH - 4 && x >= 3 && x <= WW - 4) {
#pragma unroll
        for (int j = -3; j <= 3; ++j) {
            float wy = G7c[j + 3];
#pragma unroll
            for (int i = -3; i <= 3; ++i)
                atomicAdd(cb + (y + j) * WW + (x + i), wy * G7c[i + 3]);
        }
    } else {
        int oy0 = max(y - 6, 0), oy1 = min(y + 6, HH - 1);
        int ox0 = max(x - 6, 0), ox1 = min(x + 6, WW - 1);
        for (int oy = oy0; oy <= oy1; ++oy) {
            float wy = w1d(y, oy, HH);
            if (wy == 0.f) continue;
            for (int ox = ox0; ox <= ox1; ++ox) {
                float wx = w1d(x, ox, WW);
                if (wx != 0.f) atomicAdd(cb + oy * WW + ox, wy * wx);
            }
        }
    }
}

// 9) fused BCE + laplacian regularizer; per-block partials  (float4)
__global__ void k_loss(const float* __restrict__ scores, const float* __restrict__ corners,
                       float* __restrict__ partial) {
    int g = blockIdx.x * blockDim.x + threadIdx.x;
    float bce = 0.f, reg = 0.f;
    if (g < NG) {
        int b = g / HWP4, rem = g % HWP4;
        int p = rem * 4, y = p >> 9, x0 = p & 511;
        const float* sb = scores + (size_t)b * HWP;
        float s25[4] = {0.f, 0.f, 0.f, 0.f};
        float pv[4];
        if (x0 >= 4 && x0 <= 504) {
#pragma unroll
            for (int j = -2; j <= 2; ++j) {
                int yy = reflect_idx(y + j, HH);
                const float4* q = (const float4*)(sb + (size_t)yy * WW + x0 - 4);
                float4 qa = q[0], qb = q[1], qc = q[2];
                float f[12] = {qa.x,qa.y,qa.z,qa.w, qb.x,qb.y,qb.z,qb.w, qc.x,qc.y,qc.z,qc.w};
#pragma unroll
                for (int k = 0; k < 4; ++k)
                    s25[k] += f[k+2] + f[k+3] + f[k+4] + f[k+5] + f[k+6];
                if (j == 0) { pv[0]=f[4]; pv[1]=f[5]; pv[2]=f[6]; pv[3]=f[7]; }
            }
        } else {
            for (int k = 0; k < 4; ++k) {
                int x = x0 + k;
                float s = 0.f;
                for (int j = -2; j <= 2; ++j) {
                    const float* r = sb + (size_t)reflect_idx(y + j, HH) * WW;
                    for (int i = -2; i <= 2; ++i)
                        s += r[reflect_idx(x + i, WW)];
                }
                s25[k] = s;
                pv[k] = sb[(size_t)y * WW + x];
            }
        }
        float4 c4 = ((const float4*)corners)[g];
        float cv[4] = {c4.x, c4.y, c4.z, c4.w};
#pragma unroll
        for (int k = 0; k < 4; ++k) {
            float pp = pv[k], cc = cv[k];
            float lp = __logf(pp);
            lp = (lp > -100.f) ? lp : -100.f;
            float l1p = __logf(1.f - pp);
            l1p = (l1p > -100.f) ? l1p : -100.f;
            bce += -(cc * lp + (1.f - cc) * l1p);
            float lap = (s25[k] - 25.f * pp) * (1.0f / 48.0f);
            reg += pp * __expf(-lap);
        }
    }
#pragma unroll
    for (int off = 32; off; off >>= 1) {
        bce += __shfl_down(bce, off);
        reg += __shfl_down(reg, off);
    }
    __shared__ float wb[4], wr[4];
    int wid = threadIdx.x >> 6, lid = threadIdx.x & 63;
    if (lid == 0) { wb[wid] = bce; wr[wid] = reg; }
    __syncthreads();
    if (threadIdx.x == 0) {
        float tb = 0.f, tr = 0.f;
        for (int w = 0; w < 4; ++w) { tb += wb[w]; tr += wr[w]; }
        partial[blockIdx.x] = tb;
        partial[NBL + blockIdx.x] = tr;
    }
}

// 10) reduce partials -> scalar
__global__ void k_reduce(const float* __restrict__ partial, float* __restrict__ out) {
    float tb = 0.f, tr = 0.f;
    for (int i = threadIdx.x; i < NBL; i += blockDim.x) {
        tb += partial[i];
        tr += partial[NBL + i];
    }
#pragma unroll
    for (int off = 32; off; off >>= 1) {
        tb += __shfl_down(tb, off);
        tr += __shfl_down(tr, off);
    }
    __shared__ float wb[4], wr[4];
    int wid = threadIdx.x >> 6, lid = threadIdx.x & 63;
    if (lid == 0) { wb[wid] = tb; wr[wid] = tr; }
    __syncthreads();
    if (threadIdx.x == 0) {
        float sb = 0.f, sr = 0.f;
        for (int w = 0; w < 4; ++w) { sb += wb[w]; sr += wr[w]; }
        float invN = 1.0f / (float)NPIX;
        out[0] = sb * invN + sr * invN * 10.0f;
    }
}

extern "C" void kernel_launch(void* const* d_in, const int* in_sizes, int n_in,
                              void* d_out, int out_size, void* d_ws, size_t ws_size,
                              hipStream_t stream) {
    const float* scores = (const float*)d_in[0];
    const float* imgs   = (const float*)d_in[1];
    float* out = (float*)d_out;

    float* ws = (float*)d_ws;
    float* A0 = ws;                     // gray -> S
    float* A1 = ws + (size_t)NPIX;      // ha -> hm
    float* A2 = ws + 2 * (size_t)NPIX;  // hc -> corners
    float* A3 = ws + 3 * (size_t)NPIX;  // hd -> target
    float* sval = ws + 4 * (size_t)NPIX;              // [BB][NKEY]
    int*   sidx = (int*)(sval + (size_t)BB * NKEY);
    int*   ocnt = (int*)(sidx + (size_t)BB * NKEY);   // [BB]
    unsigned long long* selK = (unsigned long long*)(ocnt + BB);  // [BB]
    float* partial = (float*)(selK + BB);             // [2*NBL]

    const int T = 256;
    const int GG = NG / T;              // 4096

    k_gray <<<GG, T, 0, stream>>>(imgs, A0);
    k_gradH<<<GG, T, 0, stream>>>(A0, A1, A2, A3);
    k_gfttV<<<GG, T, 0, stream>>>(A1, A2, A3, A0);
    k_nms1h<<<GG, T, 0, stream>>>(A0, A1);

    hipMemsetAsync(ocnt, 0, BB * sizeof(int), stream);
    dim3 gcand(16, 64, BB);
    k_cand<<<gcand, 256, 0, stream>>>(A1, A0, sval, sidx, ocnt);

    hipMemsetAsync(A3, 0, (size_t)NPIX * sizeof(float), stream);  // target
    hipMemsetAsync(A2, 0, (size_t)NPIX * sizeof(float), stream);  // corners

    k_sel1<<<BB, 256, 0, stream>>>(sval, sidx, ocnt, selK);
    const int GS = (BB * NKEY + T - 1) / T;
    k_scat<<<GS, T, 0, stream>>>(sval, sidx, ocnt, selK, A3);
    k_post<<<GS, T, 0, stream>>>(sval, sidx, ocnt, selK, A3, A2);

    k_loss  <<<NBL, T, 0, stream>>>(scores, A2, partial);
    k_reduce<<<1, 256, 0, stream>>>(partial, out);
}

// Round 6
// 329.877 us; speedup vs baseline: 1.1832x; 1.1832x over previous
//
#include <hip/hip_runtime.h>
#include <math.h>

#define BB 16
#define HH 512
#define WW 512
#define HWP (HH*WW)
#define NPIX (BB*HWP)
#define HWP4 (HWP/4)
#define NG (NPIX/4)      // number of 4-pixel groups
#define NCORN 500
#define NSLOT 4096       // 64x64 tiles of 8x8 per image
#define OCAP 1024        // overflow for exact ties with block max (rare)
#define NKEY (NSLOT+OCAP)
#define NKPT (NKEY/256)  // keys per thread in k_sel = 20
#define NBL 4096         // k_loss blocks (= NG/256)

__device__ __constant__ float G7c[7] = {
    0.0044330482f, 0.0540055826f, 0.2420362294f, 0.3990502793f,
    0.2420362294f, 0.0540055826f, 0.0044330482f};

__device__ __forceinline__ int reflect_idx(int i, int n) {
    if (i < 0) i = -i;
    if (i >= n) i = 2 * n - 2 - i;
    return i;
}

// 1D scatter weight for reflect-padded 7-tap gaussian blur:
// contribution of source p to output o (both in [0,n)).
__device__ __forceinline__ float w1d(int p, int o, int n) {
    float w = 0.f;
    int d = p - o;
    if (d >= -3 && d <= 3) w += G7c[d + 3];
    if (p >= 1 && p + o <= 3) w += G7c[3 - p - o];              // low mirror
    if (p <= n - 2 && p + o >= 2 * n - 5) w += G7c[2 * n + 1 - p - o]; // high mirror
    return w;
}

// 1) gray = 0.299 R + 0.587 G + 0.114 B  (float4)
__global__ void k_gray(const float* __restrict__ imgs, float* __restrict__ gray) {
    int g = blockIdx.x * blockDim.x + threadIdx.x;
    if (g >= NG) return;
    int b = g / HWP4, r = g % HWP4;
    const float4* base = (const float4*)(imgs + (size_t)b * 3 * HWP);
    float4 R = base[r], G = base[r + HWP4], Bc = base[r + 2 * HWP4];
    float4 o;
    o.x = 0.299f * R.x + 0.587f * G.x + 0.114f * Bc.x;
    o.y = 0.299f * R.y + 0.587f * G.y + 0.114f * Bc.y;
    o.z = 0.299f * R.z + 0.587f * G.z + 0.114f * Bc.z;
    o.w = 0.299f * R.w + 0.587f * G.w + 0.114f * Bc.w;
    ((float4*)gray)[g] = o;
}

// 2) fused sobel (replicate) + horizontal 7-tap gaussian (reflect) of products
__global__ void k_gradH(const float* __restrict__ gray,
                        float* __restrict__ ha, float* __restrict__ hc,
                        float* __restrict__ hd) {
    int g = blockIdx.x * blockDim.x + threadIdx.x;
    if (g >= NG) return;
    int b = g / HWP4, rem = g % HWP4;
    int p = rem * 4, y = p >> 9, x0 = p & 511;
    const float* gb = gray + (size_t)b * HWP;
    int ym = max(y - 1, 0), yp = min(y + 1, HH - 1);
    const float* rm = gb + (size_t)ym * WW;
    const float* rc = gb + (size_t)y * WW;
    const float* rp = gb + (size_t)yp * WW;
    if (x0 >= 4 && x0 <= 504) {
        float r0[12], r1[12], r2[12];
        const float4* q0 = (const float4*)(rm + x0 - 4);
        const float4* q1 = (const float4*)(rc + x0 - 4);
        const float4* q2 = (const float4*)(rp + x0 - 4);
#pragma unroll
        for (int t = 0; t < 3; ++t) {
            float4 a = q0[t], bq = q1[t], c = q2[t];
            r0[4*t]=a.x; r0[4*t+1]=a.y; r0[4*t+2]=a.z; r0[4*t+3]=a.w;
            r1[4*t]=bq.x; r1[4*t+1]=bq.y; r1[4*t+2]=bq.z; r1[4*t+3]=bq.w;
            r2[4*t]=c.x; r2[4*t+1]=c.y; r2[4*t+2]=c.z; r2[4*t+3]=c.w;
        }
        float dxv[10], dyv[10];
#pragma unroll
        for (int w = 1; w <= 10; ++w) {
            float dx = (r0[w+1]-r0[w-1] + 2.f*(r1[w+1]-r1[w-1]) + r2[w+1]-r2[w-1]) * 0.125f;
            float dy = (r2[w-1]-r0[w-1] + 2.f*(r2[w]-r0[w]) + r2[w+1]-r0[w+1]) * 0.125f;
            dxv[w-1] = dx; dyv[w-1] = dy;
        }
        float4 av, cv, dv;
        float* pa = (float*)&av; float* pc = (float*)&cv; float* pd = (float*)&dv;
#pragma unroll
        for (int k = 0; k < 4; ++k) {
            float a = 0.f, c = 0.f, d = 0.f;
#pragma unroll
            for (int t = -3; t <= 3; ++t) {
                int wi = k + 3 + t;
                float w = G7c[t + 3];
                a += w * dxv[wi] * dxv[wi];
                c += w * dyv[wi] * dyv[wi];
                d += w * dxv[wi] * dyv[wi];
            }
            pa[k] = a; pc[k] = c; pd[k] = d;
        }
        ((float4*)ha)[g] = av;
        ((float4*)hc)[g] = cv;
        ((float4*)hd)[g] = dv;
    } else {
        for (int k = 0; k < 4; ++k) {
            int x = x0 + k;
            float a = 0.f, c = 0.f, d = 0.f;
            for (int t = -3; t <= 3; ++t) {
                int xx = reflect_idx(x + t, WW);
                int xm = max(xx - 1, 0), xp = min(xx + 1, WW - 1);
                float g00 = rm[xm], g01 = rm[xx], g02 = rm[xp];
                float g10 = rc[xm],               g12 = rc[xp];
                float g20 = rp[xm], g21 = rp[xx], g22 = rp[xp];
                float dx = (g02 - g00 + 2.f * (g12 - g10) + g22 - g20) * 0.125f;
                float dy = (g20 - g00 + 2.f * (g21 - g01) + g22 - g02) * 0.125f;
                float w = G7c[t + 3];
                a += w * dx * dx; c += w * dy * dy; d += w * dx * dy;
            }
            size_t i = (size_t)b * HWP + p + k;
            ha[i] = a; hc[i] = c; hd[i] = d;
        }
    }
}

// 3) vertical 7-tap gaussian (reflect) + min-eigenvalue + fused horizontal 5-max
//    one block = 2 full rows (256 thr x 4 px); S kept in LDS for the row max
__global__ void k_gfttV(const float* __restrict__ ha, const float* __restrict__ hc,
                        const float* __restrict__ hd, float* __restrict__ S,
                        float* __restrict__ hm) {
    __shared__ float srow[1024];
    int b = blockIdx.x >> 8;
    int rp = blockIdx.x & 255;
    int half = threadIdx.x >> 7;
    int y = rp * 2 + half;
    int x0 = (threadIdx.x & 127) * 4;
    float4 a = {0,0,0,0}, c = {0,0,0,0}, d = {0,0,0,0};
#pragma unroll
    for (int j = -3; j <= 3; ++j) {
        int yy = reflect_idx(y + j, HH);
        float w = G7c[j + 3];
        size_t i4 = ((size_t)b * HWP + (size_t)yy * WW + x0) >> 2;
        float4 qa = ((const float4*)ha)[i4];
        float4 qc = ((const float4*)hc)[i4];
        float4 qd = ((const float4*)hd)[i4];
        a.x += w*qa.x; a.y += w*qa.y; a.z += w*qa.z; a.w += w*qa.w;
        c.x += w*qc.x; c.y += w*qc.y; c.z += w*qc.z; c.w += w*qc.w;
        d.x += w*qd.x; d.y += w*qd.y; d.z += w*qd.z; d.w += w*qd.w;
    }
    float4 o;
    float* pa = (float*)&a; float* pc = (float*)&c; float* pd = (float*)&d; float* po = (float*)&o;
#pragma unroll
    for (int k = 0; k < 4; ++k) {
        float det = pa[k] * pc[k] - pd[k] * pd[k];
        float tr = pa[k] + pc[k];
        po[k] = 0.5f * (tr - sqrtf(fabsf(tr * tr - 4.f * det)));
    }
    size_t g4 = ((size_t)b * HWP + (size_t)y * WW + x0) >> 2;
    ((float4*)S)[g4] = o;
    *((float4*)&srow[half * 512 + x0]) = o;
    __syncthreads();
    const float* row = &srow[half * 512];
    float4 hv; float* ph = (float*)&hv;
#pragma unroll
    for (int k = 0; k < 4; ++k) {
        int x = x0 + k;
        int xa = max(x - 2, 0), xb = min(x + 2, WW - 1);
        float m = -INFINITY;
        for (int xx = xa; xx <= xb; ++xx) m = fmaxf(m, row[xx]);
        ph[k] = m;
    }
    ((float4*)hm)[g4] = hv;
}

// 5) fused vertical NMS + per-8x8-tile max -> fixed slot; ties overflow
__global__ void k_cand(const float* __restrict__ hm, const float* __restrict__ S,
                       float* __restrict__ sval, int* __restrict__ sidx,
                       int* __restrict__ ocnt) {
    int wave = threadIdx.x >> 6, lane = threadIdx.x & 63;
    int tx = blockIdx.x * 4 + wave;      // tile col 0..63
    int ty = blockIdx.y;                 // tile row 0..63
    int b = blockIdx.z;
    int ly = lane >> 3, lx = lane & 7;
    int y = ty * 8 + ly, x = tx * 8 + lx;
    const float* hb = hm + (size_t)b * HWP;
    int y0 = max(y - 2, 0), y1 = min(y + 2, HH - 1);
    float m = -INFINITY;
    for (int yy = y0; yy <= y1; ++yy) m = fmaxf(m, hb[yy * WW + x]);
    float v = S[(size_t)b * HWP + y * WW + x];
    float cval = (v == m) ? v : 0.f;      // NMS result
    float tm = cval;
#pragma unroll
    for (int off = 32; off; off >>= 1)
        tm = fmaxf(tm, __shfl_xor(tm, off));
    unsigned long long mask = __ballot(cval == tm && cval > 0.f);
    int slot = ty * 64 + tx;
    if (mask) {
        int first = __ffsll(mask) - 1;
        if (lane == first) {
            sval[b * NKEY + slot] = cval;
            sidx[b * NKEY + slot] = y * WW + x;
        } else if ((mask >> lane) & 1ull) {
            int pos = atomicAdd(&ocnt[b], 1);
            if (pos < OCAP) {
                sval[b * NKEY + NSLOT + pos] = cval;
                sidx[b * NKEY + NSLOT + pos] = y * WW + x;
            }
        }
    } else if (lane == 0) {
        sval[b * NKEY + slot] = 0.f;
        sidx[b * NKEY + slot] = 0;
    }
}

// 6) exact 500th-largest 64-bit key per image via atomic-free MSB bit-descent.
//    Keys held in registers (static unroll); per-step block count via shfl+LDS.
__global__ __launch_bounds__(256) void k_sel(const float* __restrict__ sval,
                       const int* __restrict__ sidx, const int* __restrict__ ocnt,
                       unsigned long long* __restrict__ selK) {
    __shared__ int shw[4];
    __shared__ int shtot;
    int b = blockIdx.x;
    int n = NSLOT + min(ocnt[b], OCAP);
    unsigned long long keys[NKPT];
    int cnt = 0;
#pragma unroll
    for (int t = 0; t < NKPT; ++t) {
        int i = threadIdx.x + t * 256;
        unsigned long long k = 0ull;
        if (i < n) {
            float v = sval[b * NKEY + i];
            if (v > 0.f) {
                unsigned int ix = (unsigned int)sidx[b * NKEY + i];
                k = ((unsigned long long)__float_as_uint(v) << 32) |
                    (unsigned long long)(~ix);
                cnt++;
            }
        }
        keys[t] = k;
    }
    int wid = threadIdx.x >> 6;
    {
        int c = cnt;
#pragma unroll
        for (int off = 32; off; off >>= 1) c += __shfl_down(c, off);
        if ((threadIdx.x & 63) == 0) shw[wid] = c;
        __syncthreads();
        if (threadIdx.x == 0) shtot = shw[0] + shw[1] + shw[2] + shw[3];
        __syncthreads();
    }
    int target = min(NCORN, shtot);
    unsigned long long T = 0ull;
    for (int bit = 63; bit >= 0; --bit) {
        unsigned long long cand = T | (1ull << bit);
        int c = 0;
#pragma unroll
        for (int t = 0; t < NKPT; ++t) c += (keys[t] >= cand) ? 1 : 0;
#pragma unroll
        for (int off = 32; off; off >>= 1) c += __shfl_down(c, off);
        __syncthreads();              // protect shw from previous iteration's reads
        if ((threadIdx.x & 63) == 0) shw[wid] = c;
        __syncthreads();
        int tot = shw[0] + shw[1] + shw[2] + shw[3];
        if (tot >= target) T = cand;
    }
    if (threadIdx.x == 0) selK[b] = T;
}

// 7) sparse second NMS from the candidate list itself + gaussian stamp.
//    A selected point is suppressed only by a SELECTED, strictly-greater
//    candidate within cheb<=2, which must be the slot-max of one of <=4
//    adjacent tiles (or an overflow tie entry, ~never).
__global__ void k_post(const float* __restrict__ sval, const int* __restrict__ sidx,
                       const int* __restrict__ ocnt, const unsigned long long* __restrict__ selK,
                       float* __restrict__ corners) {
    int gid = blockIdx.x * blockDim.x + threadIdx.x;
    if (gid >= BB * NKEY) return;
    int b = gid / NKEY, s = gid % NKEY;
    int novf = min(ocnt[b], OCAP);
    if (s >= NSLOT + novf) return;
    float v = sval[gid];
    if (v <= 0.f) return;
    unsigned int ix = (unsigned int)sidx[gid];
    unsigned long long K = selK[b];
    unsigned long long k = ((unsigned long long)__float_as_uint(v) << 32) |
                           (unsigned long long)(~ix);
    if (k < K) return;                       // not in top-500
    int y = (int)(ix >> 9), x = (int)(ix & 511);
    const float* bsv = sval + b * NKEY;
    const int* bsi = sidx + b * NKEY;
    bool sup = false;
    int ty0 = max(y - 2, 0) >> 3, ty1 = min(y + 2, HH - 1) >> 3;
    int tx0 = max(x - 2, 0) >> 3, tx1 = min(x + 2, WW - 1) >> 3;
    for (int ty = ty0; ty <= ty1 && !sup; ++ty)
        for (int tx = tx0; tx <= tx1 && !sup; ++tx) {
            int s2 = ty * 64 + tx;
            float v2 = bsv[s2];
            if (v2 <= v) continue;           // equal never suppresses (t==m kept)
            int ix2 = bsi[s2];
            unsigned long long k2 = ((unsigned long long)__float_as_uint(v2) << 32) |
                                    (unsigned long long)(~(unsigned int)ix2);
            if (k2 < K) continue;            // neighbor not selected
            int y2 = ix2 >> 9, x2 = ix2 & 511;
            if (abs(y2 - y) <= 2 && abs(x2 - x) <= 2) sup = true;
        }
    for (int j = 0; j < novf && !sup; ++j) {
        float v2 = bsv[NSLOT + j];
        if (v2 <= v) continue;
        int ix2 = bsi[NSLOT + j];
        unsigned long long k2 = ((unsigned long long)__float_as_uint(v2) << 32) |
                                (unsigned long long)(~(unsigned int)ix2);
        if (k2 < K) continue;
        int y2 = ix2 >> 9, x2 = ix2 & 511;
        if (abs(y2 - y) <= 2 && abs(x2 - x) <= 2) sup = true;
    }
    if (sup) return;
    // stamp 7x7 reflect-pad gaussian of a unit impulse at (y,x)
    float* cb = corners + (size_t)b * HWP;
    if (y >= 3 && y <= HH - 4 && x >= 3 && x <= WW - 4) {
#pragma unroll
        for (int j = -3; j <= 3; ++j) {
            float wy = G7c[j + 3];
#pragma unroll
            for (int i = -3; i <= 3; ++i)
                atomicAdd(cb + (y + j) * WW + (x + i), wy * G7c[i + 3]);
        }
    } else {
        int oy0 = max(y - 6, 0), oy1 = min(y + 6, HH - 1);
        int ox0 = max(x - 6, 0), ox1 = min(x + 6, WW - 1);
        for (int oy = oy0; oy <= oy1; ++oy) {
            float wy = w1d(y, oy, HH);
            if (wy == 0.f) continue;
            for (int ox = ox0; ox <= ox1; ++ox) {
                float wx = w1d(x, ox, WW);
                if (wx != 0.f) atomicAdd(cb + oy * WW + ox, wy * wx);
            }
        }
    }
}

// 9) fused BCE + laplacian regularizer; per-block partials  (float4)
__global__ void k_loss(const float* __restrict__ scores, const float* __restrict__ corners,
                       float* __restrict__ partial) {
    int g = blockIdx.x * blockDim.x + threadIdx.x;
    float bce = 0.f, reg = 0.f;
    if (g < NG) {
        int b = g / HWP4, rem = g % HWP4;
        int p = rem * 4, y = p >> 9, x0 = p & 511;
        const float* sb = scores + (size_t)b * HWP;
        float s25[4] = {0.f, 0.f, 0.f, 0.f};
        float pv[4];
        if (x0 >= 4 && x0 <= 504) {
#pragma unroll
            for (int j = -2; j <= 2; ++j) {
                int yy = reflect_idx(y + j, HH);
                const float4* q = (const float4*)(sb + (size_t)yy * WW + x0 - 4);
                float4 qa = q[0], qb = q[1], qc = q[2];
                float f[12] = {qa.x,qa.y,qa.z,qa.w, qb.x,qb.y,qb.z,qb.w, qc.x,qc.y,qc.z,qc.w};
#pragma unroll
                for (int k = 0; k < 4; ++k)
                    s25[k] += f[k+2] + f[k+3] + f[k+4] + f[k+5] + f[k+6];
                if (j == 0) { pv[0]=f[4]; pv[1]=f[5]; pv[2]=f[6]; pv[3]=f[7]; }
            }
        } else {
            for (int k = 0; k < 4; ++k) {
                int x = x0 + k;
                float s = 0.f;
                for (int j = -2; j <= 2; ++j) {
                    const float* r = sb + (size_t)reflect_idx(y + j, HH) * WW;
                    for (int i = -2; i <= 2; ++i)
                        s += r[reflect_idx(x + i, WW)];
                }
                s25[k] = s;
                pv[k] = sb[(size_t)y * WW + x];
            }
        }
        float4 c4 = ((const float4*)corners)[g];
        float cv[4] = {c4.x, c4.y, c4.z, c4.w};
#pragma unroll
        for (int k = 0; k < 4; ++k) {
            float pp = pv[k], cc = cv[k];
            float lp = __logf(pp);
            lp = (lp > -100.f) ? lp : -100.f;
            float l1p = __logf(1.f - pp);
            l1p = (l1p > -100.f) ? l1p : -100.f;
            bce += -(cc * lp + (1.f - cc) * l1p);
            float lap = (s25[k] - 25.f * pp) * (1.0f / 48.0f);
            reg += pp * __expf(-lap);
        }
    }
#pragma unroll
    for (int off = 32; off; off >>= 1) {
        bce += __shfl_down(bce, off);
        reg += __shfl_down(reg, off);
    }
    __shared__ float wb[4], wr[4];
    int wid = threadIdx.x >> 6, lid = threadIdx.x & 63;
    if (lid == 0) { wb[wid] = bce; wr[wid] = reg; }
    __syncthreads();
    if (threadIdx.x == 0) {
        float tb = 0.f, tr = 0.f;
        for (int w = 0; w < 4; ++w) { tb += wb[w]; tr += wr[w]; }
        partial[blockIdx.x] = tb;
        partial[NBL + blockIdx.x] = tr;
    }
}

// 10) reduce partials -> scalar
__global__ void k_reduce(const float* __restrict__ partial, float* __restrict__ out) {
    float tb = 0.f, tr = 0.f;
    for (int i = threadIdx.x; i < NBL; i += blockDim.x) {
        tb += partial[i];
        tr += partial[NBL + i];
    }
#pragma unroll
    for (int off = 32; off; off >>= 1) {
        tb += __shfl_down(tb, off);
        tr += __shfl_down(tr, off);
    }
    __shared__ float wb[4], wr[4];
    int wid = threadIdx.x >> 6, lid = threadIdx.x & 63;
    if (lid == 0) { wb[wid] = tb; wr[wid] = tr; }
    __syncthreads();
    if (threadIdx.x == 0) {
        float sb = 0.f, sr = 0.f;
        for (int w = 0; w < 4; ++w) { sb += wb[w]; sr += wr[w]; }
        float invN = 1.0f / (float)NPIX;
        out[0] = sb * invN + sr * invN * 10.0f;
    }
}

extern "C" void kernel_launch(void* const* d_in, const int* in_sizes, int n_in,
                              void* d_out, int out_size, void* d_ws, size_t ws_size,
                              hipStream_t stream) {
    const float* scores = (const float*)d_in[0];
    const float* imgs   = (const float*)d_in[1];
    float* out = (float*)d_out;

    float* ws = (float*)d_ws;
    float* A0 = ws;                     // gray -> S
    float* A1 = ws + (size_t)NPIX;      // ha -> hm
    float* A2 = ws + 2 * (size_t)NPIX;  // hc -> corners
    float* A3 = ws + 3 * (size_t)NPIX;  // hd
    float* sval = ws + 4 * (size_t)NPIX;              // [BB][NKEY]
    int*   sidx = (int*)(sval + (size_t)BB * NKEY);
    int*   ocnt = (int*)(sidx + (size_t)BB * NKEY);   // [BB]
    unsigned long long* selK = (unsigned long long*)(ocnt + BB);  // [BB]
    float* partial = (float*)(selK + BB);             // [2*NBL]

    const int T = 256;
    const int GG = NG / T;              // 4096

    k_gray <<<GG, T, 0, stream>>>(imgs, A0);
    k_gradH<<<GG, T, 0, stream>>>(A0, A1, A2, A3);
    k_gfttV<<<BB * (HH / 2), 256, 0, stream>>>(A1, A2, A3, A0, A1);  // S->A0, hm->A1

    hipMemsetAsync(ocnt, 0, BB * sizeof(int), stream);
    dim3 gcand(16, 64, BB);
    k_cand<<<gcand, 256, 0, stream>>>(A1, A0, sval, sidx, ocnt);

    hipMemsetAsync(A2, 0, (size_t)NPIX * sizeof(float), stream);  // corners

    k_sel<<<BB, 256, 0, stream>>>(sval, sidx, ocnt, selK);
    const int GS = (BB * NKEY + T - 1) / T;
    k_post<<<GS, T, 0, stream>>>(sval, sidx, ocnt, selK, A2);

    k_loss  <<<NBL, T, 0, stream>>>(scores, A2, partial);
    k_reduce<<<1, 256, 0, stream>>>(partial, out);
}

// Round 7
// 293.564 us; speedup vs baseline: 1.3295x; 1.1237x over previous
//
#include <hip/hip_runtime.h>
#include <math.h>

#define BB 16
#define HH 512
#define WW 512
#define HWP (HH*WW)
#define NPIX (BB*HWP)
#define HWP4 (HWP/4)
#define NG (NPIX/4)      // number of 4-pixel groups
#define NCORN 500
#define NSLOT 4096       // 64x64 tiles of 8x8 per image
#define OCAP 1024        // overflow for exact ties with block max (rare)
#define NKEY (NSLOT+OCAP)
#define NKPT (NKEY/256)  // keys per thread in k_sel = 20
#define NBL 4096         // k_loss blocks (= NG/256)

__device__ __constant__ float G7c[7] = {
    0.0044330482f, 0.0540055826f, 0.2420362294f, 0.3990502793f,
    0.2420362294f, 0.0540055826f, 0.0044330482f};

__device__ __forceinline__ int reflect_idx(int i, int n) {
    if (i < 0) i = -i;
    if (i >= n) i = 2 * n - 2 - i;
    return i;
}

// 1D scatter weight for reflect-padded 7-tap gaussian blur:
// contribution of source p to output o (both in [0,n)).
__device__ __forceinline__ float w1d(int p, int o, int n) {
    float w = 0.f;
    int d = p - o;
    if (d >= -3 && d <= 3) w += G7c[d + 3];
    if (p >= 1 && p + o <= 3) w += G7c[3 - p - o];              // low mirror
    if (p <= n - 2 && p + o >= 2 * n - 5) w += G7c[2 * n + 1 - p - o]; // high mirror
    return w;
}

// 1) gray = 0.299 R + 0.587 G + 0.114 B  (float4)
__global__ void k_gray(const float* __restrict__ imgs, float* __restrict__ gray) {
    int g = blockIdx.x * blockDim.x + threadIdx.x;
    if (g >= NG) return;
    int b = g / HWP4, r = g % HWP4;
    const float4* base = (const float4*)(imgs + (size_t)b * 3 * HWP);
    float4 R = base[r], G = base[r + HWP4], Bc = base[r + 2 * HWP4];
    float4 o;
    o.x = 0.299f * R.x + 0.587f * G.x + 0.114f * Bc.x;
    o.y = 0.299f * R.y + 0.587f * G.y + 0.114f * Bc.y;
    o.z = 0.299f * R.z + 0.587f * G.z + 0.114f * Bc.z;
    o.w = 0.299f * R.w + 0.587f * G.w + 0.114f * Bc.w;
    ((float4*)gray)[g] = o;
}

// 2) fused sobel (replicate) + H 7-tap blur + V 7-tap blur + min-eig.
//    Thread = 4-col strip of an 8-row band; 7-row V window in registers.
//    All array indices static via full unroll.
__global__ __launch_bounds__(256) void k_front(const float* __restrict__ gray,
                                               float* __restrict__ S) {
    int gid = blockIdx.x * 256 + threadIdx.x;
    int cstrip = gid & 127;
    int band = (gid >> 7) & 63;
    int b = gid >> 13;
    int x0 = cstrip * 4;
    int y0 = band * 8;
    const float* gb = gray + (size_t)b * HWP;
    float* Sb = S + (size_t)b * HWP;
    bool edgeL = (x0 == 0), edgeR = (x0 == 508);

    float aA[7][4], aC[7][4], aD[7][4];
#pragma unroll
    for (int s = 0; s < 7; ++s)
#pragma unroll
        for (int k = 0; k < 4; ++k) { aA[s][k] = 0.f; aC[s][k] = 0.f; aD[s][k] = 0.f; }

#pragma unroll
    for (int i = 0; i < 14; ++i) {
        int tp = y0 - 3 + i;                 // vblur tap position (reflect below)
        int src = reflect_idx(tp, HH);       // product source row
        int r0 = max(src - 1, 0), r2 = min(src + 1, HH - 1);  // sobel replicate
        float G[3][12];
        {
            const float* rw0 = gb + (size_t)r0 * WW;
            const float* rw1 = gb + (size_t)src * WW;
            const float* rw2 = gb + (size_t)r2 * WW;
            const float* rws[3] = {rw0, rw1, rw2};
#pragma unroll
            for (int r = 0; r < 3; ++r) {
                const float* rw = rws[r];
                float4 own = *(const float4*)(rw + x0);
                G[r][4] = own.x; G[r][5] = own.y; G[r][6] = own.z; G[r][7] = own.w;
                if (!edgeL) {
                    float4 lf = *(const float4*)(rw + x0 - 4);
                    G[r][0] = lf.x; G[r][1] = lf.y; G[r][2] = lf.z; G[r][3] = lf.w;
                } else {
                    G[r][0] = 0.f; G[r][1] = 0.f; G[r][2] = 0.f;
                    G[r][3] = own.x;             // gray(-1) -> clamp -> gray(0)
                }
                if (!edgeR) {
                    float4 rt = *(const float4*)(rw + x0 + 4);
                    G[r][8] = rt.x; G[r][9] = rt.y; G[r][10] = rt.z; G[r][11] = rt.w;
                } else {
                    G[r][8] = own.w;             // gray(512) -> clamp -> gray(511)
                    G[r][9] = 0.f; G[r][10] = 0.f; G[r][11] = 0.f;
                }
            }
        }
        // sobel products at 10 positions x0-3 .. x0+6
        float pa[10], pc[10], pd[10];
#pragma unroll
        for (int j = 0; j < 10; ++j) {
            int gi = j + 1;
            float dx = (G[0][gi+1] - G[0][gi-1] + 2.f * (G[1][gi+1] - G[1][gi-1])
                        + G[2][gi+1] - G[2][gi-1]) * 0.125f;
            float dy = (G[2][gi-1] - G[0][gi-1] + 2.f * (G[2][gi] - G[0][gi])
                        + G[2][gi+1] - G[0][gi+1]) * 0.125f;
            pa[j] = dx * dx; pc[j] = dy * dy; pd[j] = dx * dy;
        }
        if (edgeL) {   // reflect: pos -1,-2,-3 <- pos 1,2,3
            pa[2] = pa[4]; pc[2] = pc[4]; pd[2] = pd[4];
            pa[1] = pa[5]; pc[1] = pc[5]; pd[1] = pd[5];
            pa[0] = pa[6]; pc[0] = pc[6]; pd[0] = pd[6];
        }
        if (edgeR) {   // reflect: pos 512,513,514 <- pos 510,509,508
            pa[7] = pa[5]; pc[7] = pc[5]; pd[7] = pd[5];
            pa[8] = pa[4]; pc[8] = pc[4]; pd[8] = pd[4];
            pa[9] = pa[3]; pc[9] = pc[3]; pd[9] = pd[3];
        }
        // horizontal 7-tap blur
        float hA[4], hC[4], hD[4];
#pragma unroll
        for (int k = 0; k < 4; ++k) {
            float A = 0.f, C = 0.f, D = 0.f;
#pragma unroll
            for (int t = 0; t < 7; ++t) {
                float w = G7c[t];
                A += w * pa[k + t]; C += w * pc[k + t]; D += w * pd[k + t];
            }
            hA[k] = A; hC[k] = C; hD[k] = D;
        }
        // vertical accumulate into rolling 7 accumulators (static slots)
#pragma unroll
        for (int d2 = 0; d2 < 7; ++d2) {
            int l = i - 6 + d2;
            if (l < 0 || l > 7) continue;     // compile-time guard
            float w = G7c[6 - d2];
#pragma unroll
            for (int k = 0; k < 4; ++k) {
                aA[l % 7][k] += w * hA[k];
                aC[l % 7][k] += w * hC[k];
                aD[l % 7][k] += w * hD[k];
            }
        }
        // emit completed row
        if (i >= 6) {
            int l = i - 6, s = l % 7;
            float4 o; float* po = (float*)&o;
#pragma unroll
            for (int k = 0; k < 4; ++k) {
                float det = aA[s][k] * aC[s][k] - aD[s][k] * aD[s][k];
                float tr = aA[s][k] + aC[s][k];
                po[k] = 0.5f * (tr - sqrtf(fabsf(tr * tr - 4.f * det)));
                aA[s][k] = 0.f; aC[s][k] = 0.f; aD[s][k] = 0.f;
            }
            *(float4*)(Sb + (size_t)(y0 + l) * WW + x0) = o;
        }
    }
}

// 3) per-wave 12x12 S tile in LDS -> 5x5 NMS + per-8x8-tile max -> slot
__global__ void k_cand2(const float* __restrict__ S, float* __restrict__ sval,
                        int* __restrict__ sidx, int* __restrict__ ocnt) {
    __shared__ float tile[4][12][12];
    int wave = threadIdx.x >> 6, lane = threadIdx.x & 63;
    int tx = blockIdx.x * 4 + wave;      // tile col 0..63
    int ty = blockIdx.y;                 // tile row 0..63
    int b = blockIdx.z;
    const float* sb = S + (size_t)b * HWP;
    for (int t = lane; t < 144; t += 64) {
        int r = t / 12, c = t % 12;
        int yy = min(max(ty * 8 - 2 + r, 0), HH - 1);
        int xx = min(max(tx * 8 - 2 + c, 0), WW - 1);
        tile[wave][r][c] = sb[yy * WW + xx];
    }
    __syncthreads();
    int ly = lane >> 3, lx = lane & 7;
    float v = tile[wave][ly + 2][lx + 2];
    float m = -INFINITY;
#pragma unroll
    for (int dy = 0; dy < 5; ++dy)
#pragma unroll
        for (int dx = 0; dx < 5; ++dx)
            m = fmaxf(m, tile[wave][ly + dy][lx + dx]);
    float cval = (v == m) ? v : 0.f;
    int y = ty * 8 + ly, x = tx * 8 + lx;
    float tm = cval;
#pragma unroll
    for (int off = 32; off; off >>= 1)
        tm = fmaxf(tm, __shfl_xor(tm, off));
    unsigned long long mask = __ballot(cval == tm && cval > 0.f);
    int slot = ty * 64 + tx;
    if (mask) {
        int first = __ffsll(mask) - 1;
        if (lane == first) {
            sval[b * NKEY + slot] = cval;
            sidx[b * NKEY + slot] = y * WW + x;
        } else if ((mask >> lane) & 1ull) {
            int pos = atomicAdd(&ocnt[b], 1);
            if (pos < OCAP) {
                sval[b * NKEY + NSLOT + pos] = cval;
                sidx[b * NKEY + NSLOT + pos] = y * WW + x;
            }
        }
    } else if (lane == 0) {
        sval[b * NKEY + slot] = 0.f;
        sidx[b * NKEY + slot] = 0;
    }
}

// 4) exact 500th-largest 64-bit key per image via atomic-free MSB bit-descent
__global__ __launch_bounds__(256) void k_sel(const float* __restrict__ sval,
                       const int* __restrict__ sidx, const int* __restrict__ ocnt,
                       unsigned long long* __restrict__ selK) {
    __shared__ int shw[4];
    __shared__ int shtot;
    int b = blockIdx.x;
    int n = NSLOT + min(ocnt[b], OCAP);
    unsigned long long keys[NKPT];
    int cnt = 0;
#pragma unroll
    for (int t = 0; t < NKPT; ++t) {
        int i = threadIdx.x + t * 256;
        unsigned long long k = 0ull;
        if (i < n) {
            float v = sval[b * NKEY + i];
            if (v > 0.f) {
                unsigned int ix = (unsigned int)sidx[b * NKEY + i];
                k = ((unsigned long long)__float_as_uint(v) << 32) |
                    (unsigned long long)(~ix);
                cnt++;
            }
        }
        keys[t] = k;
    }
    int wid = threadIdx.x >> 6;
    {
        int c = cnt;
#pragma unroll
        for (int off = 32; off; off >>= 1) c += __shfl_down(c, off);
        if ((threadIdx.x & 63) == 0) shw[wid] = c;
        __syncthreads();
        if (threadIdx.x == 0) shtot = shw[0] + shw[1] + shw[2] + shw[3];
        __syncthreads();
    }
    int target = min(NCORN, shtot);
    unsigned long long T = 0ull;
    for (int bit = 63; bit >= 0; --bit) {
        unsigned long long cand = T | (1ull << bit);
        int c = 0;
#pragma unroll
        for (int t = 0; t < NKPT; ++t) c += (keys[t] >= cand) ? 1 : 0;
#pragma unroll
        for (int off = 32; off; off >>= 1) c += __shfl_down(c, off);
        __syncthreads();
        if ((threadIdx.x & 63) == 0) shw[wid] = c;
        __syncthreads();
        int tot = shw[0] + shw[1] + shw[2] + shw[3];
        if (tot >= target) T = cand;
    }
    if (threadIdx.x == 0) selK[b] = T;
}

// 5) sparse second NMS from candidate list + gaussian stamp into corners
__global__ void k_post(const float* __restrict__ sval, const int* __restrict__ sidx,
                       const int* __restrict__ ocnt, const unsigned long long* __restrict__ selK,
                       float* __restrict__ corners) {
    int gid = blockIdx.x * blockDim.x + threadIdx.x;
    if (gid >= BB * NKEY) return;
    int b = gid / NKEY, s = gid % NKEY;
    int novf = min(ocnt[b], OCAP);
    if (s >= NSLOT + novf) return;
    float v = sval[gid];
    if (v <= 0.f) return;
    unsigned int ix = (unsigned int)sidx[gid];
    unsigned long long K = selK[b];
    unsigned long long k = ((unsigned long long)__float_as_uint(v) << 32) |
                           (unsigned long long)(~ix);
    if (k < K) return;                       // not in top-500
    int y = (int)(ix >> 9), x = (int)(ix & 511);
    const float* bsv = sval + b * NKEY;
    const int* bsi = sidx + b * NKEY;
    bool sup = false;
    int ty0 = max(y - 2, 0) >> 3, ty1 = min(y + 2, HH - 1) >> 3;
    int tx0 = max(x - 2, 0) >> 3, tx1 = min(x + 2, WW - 1) >> 3;
    for (int ty = ty0; ty <= ty1 && !sup; ++ty)
        for (int tx = tx0; tx <= tx1 && !sup; ++tx) {
            int s2 = ty * 64 + tx;
            float v2 = bsv[s2];
            if (v2 <= v) continue;           // equal never suppresses
            int ix2 = bsi[s2];
            unsigned long long k2 = ((unsigned long long)__float_as_uint(v2) << 32) |
                                    (unsigned long long)(~(unsigned int)ix2);
            if (k2 < K) continue;            // neighbor not selected
            int y2 = ix2 >> 9, x2 = ix2 & 511;
            if (abs(y2 - y) <= 2 && abs(x2 - x) <= 2) sup = true;
        }
    for (int j = 0; j < novf && !sup; ++j) {
        float v2 = bsv[NSLOT + j];
        if (v2 <= v) continue;
        int ix2 = bsi[NSLOT + j];
        unsigned long long k2 = ((unsigned long long)__float_as_uint(v2) << 32) |
                                (unsigned long long)(~(unsigned int)ix2);
        if (k2 < K) continue;
        int y2 = ix2 >> 9, x2 = ix2 & 511;
        if (abs(y2 - y) <= 2 && abs(x2 - x) <= 2) sup = true;
    }
    if (sup) return;
    float* cb = corners + (size_t)b * HWP;
    if (y >= 3 && y <= HH - 4 && x >= 3 && x <= WW - 4) {
#pragma unroll
        for (int j = -3; j <= 3; ++j) {
            float wy = G7c[j + 3];
#pragma unroll
            for (int i = -3; i <= 3; ++i)
                atomicAdd(cb + (y + j) * WW + (x + i), wy * G7c[i + 3]);
        }
    } else {
        int oy0 = max(y - 6, 0), oy1 = min(y + 6, HH - 1);
        int ox0 = max(x - 6, 0), ox1 = min(x + 6, WW - 1);
        for (int oy = oy0; oy <= oy1; ++oy) {
            float wy = w1d(y, oy, HH);
            if (wy == 0.f) continue;
            for (int ox = ox0; ox <= ox1; ++ox) {
                float wx = w1d(x, ox, WW);
                if (wx != 0.f) atomicAdd(cb + oy * WW + ox, wy * wx);
            }
        }
    }
}

// 6) fused BCE + laplacian regularizer; per-block partials  (float4)
__global__ void k_loss(const float* __restrict__ scores, const float* __restrict__ corners,
                       float* __restrict__ partial) {
    int g = blockIdx.x * blockDim.x + threadIdx.x;
    float bce = 0.f, reg = 0.f;
    if (g < NG) {
        int b = g / HWP4, rem = g % HWP4;
        int p = rem * 4, y = p >> 9, x0 = p & 511;
        const float* sb = scores + (size_t)b * HWP;
        float s25[4] = {0.f, 0.f, 0.f, 0.f};
        float pv[4];
        if (x0 >= 4 && x0 <= 504) {
#pragma unroll
            for (int j = -2; j <= 2; ++j) {
                int yy = reflect_idx(y + j, HH);
                const float4* q = (const float4*)(sb + (size_t)yy * WW + x0 - 4);
                float4 qa = q[0], qb = q[1], qc = q[2];
                float f[12] = {qa.x,qa.y,qa.z,qa.w, qb.x,qb.y,qb.z,qb.w, qc.x,qc.y,qc.z,qc.w};
#pragma unroll
                for (int k = 0; k < 4; ++k)
                    s25[k] += f[k+2] + f[k+3] + f[k+4] + f[k+5] + f[k+6];
                if (j == 0) { pv[0]=f[4]; pv[1]=f[5]; pv[2]=f[6]; pv[3]=f[7]; }
            }
        } else {
            for (int k = 0; k < 4; ++k) {
                int x = x0 + k;
                float s = 0.f;
                for (int j = -2; j <= 2; ++j) {
                    const float* r = sb + (size_t)reflect_idx(y + j, HH) * WW;
                    for (int i = -2; i <= 2; ++i)
                        s += r[reflect_idx(x + i, WW)];
                }
                s25[k] = s;
                pv[k] = sb[(size_t)y * WW + x];
            }
        }
        float4 c4 = ((const float4*)corners)[g];
        float cv[4] = {c4.x, c4.y, c4.z, c4.w};
#pragma unroll
        for (int k = 0; k < 4; ++k) {
            float pp = pv[k], cc = cv[k];
            float lp = __logf(pp);
            lp = (lp > -100.f) ? lp : -100.f;
            float l1p = __logf(1.f - pp);
            l1p = (l1p > -100.f) ? l1p : -100.f;
            bce += -(cc * lp + (1.f - cc) * l1p);
            float lap = (s25[k] - 25.f * pp) * (1.0f / 48.0f);
            reg += pp * __expf(-lap);
        }
    }
#pragma unroll
    for (int off = 32; off; off >>= 1) {
        bce += __shfl_down(bce, off);
        reg += __shfl_down(reg, off);
    }
    __shared__ float wb[4], wr[4];
    int wid = threadIdx.x >> 6, lid = threadIdx.x & 63;
    if (lid == 0) { wb[wid] = bce; wr[wid] = reg; }
    __syncthreads();
    if (threadIdx.x == 0) {
        float tb = 0.f, tr = 0.f;
        for (int w = 0; w < 4; ++w) { tb += wb[w]; tr += wr[w]; }
        partial[blockIdx.x] = tb;
        partial[NBL + blockIdx.x] = tr;
    }
}

// 7) reduce partials -> scalar
__global__ void k_reduce(const float* __restrict__ partial, float* __restrict__ out) {
    float tb = 0.f, tr = 0.f;
    for (int i = threadIdx.x; i < NBL; i += blockDim.x) {
        tb += partial[i];
        tr += partial[NBL + i];
    }
#pragma unroll
    for (int off = 32; off; off >>= 1) {
        tb += __shfl_down(tb, off);
        tr += __shfl_down(tr, off);
    }
    __shared__ float wb[4], wr[4];
    int wid = threadIdx.x >> 6, lid = threadIdx.x & 63;
    if (lid == 0) { wb[wid] = tb; wr[wid] = tr; }
    __syncthreads();
    if (threadIdx.x == 0) {
        float sb = 0.f, sr = 0.f;
        for (int w = 0; w < 4; ++w) { sb += wb[w]; sr += wr[w]; }
        float invN = 1.0f / (float)NPIX;
        out[0] = sb * invN + sr * invN * 10.0f;
    }
}

extern "C" void kernel_launch(void* const* d_in, const int* in_sizes, int n_in,
                              void* d_out, int out_size, void* d_ws, size_t ws_size,
                              hipStream_t stream) {
    const float* scores = (const float*)d_in[0];
    const float* imgs   = (const float*)d_in[1];
    float* out = (float*)d_out;

    float* ws = (float*)d_ws;
    float* A0 = ws;                     // gray
    float* A1 = ws + (size_t)NPIX;      // S
    float* A2 = ws + 2 * (size_t)NPIX;  // corners
    float* sval = ws + 3 * (size_t)NPIX;              // [BB][NKEY]
    int*   sidx = (int*)(sval + (size_t)BB * NKEY);
    int*   ocnt = (int*)(sidx + (size_t)BB * NKEY);   // [BB]
    unsigned long long* selK = (unsigned long long*)(ocnt + BB);  // [BB]
    float* partial = (float*)(selK + BB);             // [2*NBL]

    const int T = 256;
    const int GG = NG / T;              // 4096

    k_gray <<<GG, T, 0, stream>>>(imgs, A0);
    k_front<<<BB * 64 * 128 / T, T, 0, stream>>>(A0, A1);   // 512 blocks

    hipMemsetAsync(ocnt, 0, BB * sizeof(int), stream);
    dim3 gcand(16, 64, BB);
    k_cand2<<<gcand, 256, 0, stream>>>(A1, sval, sidx, ocnt);

    hipMemsetAsync(A2, 0, (size_t)NPIX * sizeof(float), stream);  // corners

    k_sel<<<BB, 256, 0, stream>>>(sval, sidx, ocnt, selK);
    const int GS = (BB * NKEY + T - 1) / T;
    k_post<<<GS, T, 0, stream>>>(sval, sidx, ocnt, selK, A2);

    k_loss  <<<NBL, T, 0, stream>>>(scores, A2, partial);
    k_reduce<<<1, 256, 0, stream>>>(partial, out);
}

// Round 8
// 266.635 us; speedup vs baseline: 1.4638x; 1.1010x over previous
//
#include <hip/hip_runtime.h>
#include <math.h>

#define BB 16
#define HH 512
#define WW 512
#define HWP (HH*WW)
#define NPIX (BB*HWP)
#define HWP4 (HWP/4)
#define NG (NPIX/4)
#define NCORN 500
#define NSLOT 4096       // 64x64 tiles of 8x8 per image
#define OCAP 1024        // overflow for exact ties with block max (rare)
#define NKEY (NSLOT+OCAP)
#define NKPT (NKEY/256)  // keys per thread in k_sel = 20
#define NBL 2048         // k_loss blocks
#define NPOSTB 320       // k_post blocks (= BB*NKEY/256)

__device__ __constant__ float G7c[7] = {
    0.0044330482f, 0.0540055826f, 0.2420362294f, 0.3990502793f,
    0.2420362294f, 0.0540055826f, 0.0044330482f};

__device__ __forceinline__ int reflect_idx(int i, int n) {
    if (i < 0) i = -i;
    if (i >= n) i = 2 * n - 2 - i;
    return i;
}

// 1D scatter weight for reflect-padded 7-tap gaussian blur
__device__ __forceinline__ float w1d(int p, int o, int n) {
    float w = 0.f;
    int d = p - o;
    if (d >= -3 && d <= 3) w += G7c[d + 3];
    if (p >= 1 && p + o <= 3) w += G7c[3 - p - o];
    if (p <= n - 2 && p + o >= 2 * n - 5) w += G7c[2 * n + 1 - p - o];
    return w;
}

// 1) gray = 0.299 R + 0.587 G + 0.114 B  (float4)
__global__ void k_gray(const float* __restrict__ imgs, float* __restrict__ gray) {
    int g = blockIdx.x * blockDim.x + threadIdx.x;
    if (g >= NG) return;
    int b = g / HWP4, r = g % HWP4;
    const float4* base = (const float4*)(imgs + (size_t)b * 3 * HWP);
    float4 R = base[r], G = base[r + HWP4], Bc = base[r + 2 * HWP4];
    float4 o;
    o.x = 0.299f * R.x + 0.587f * G.x + 0.114f * Bc.x;
    o.y = 0.299f * R.y + 0.587f * G.y + 0.114f * Bc.y;
    o.z = 0.299f * R.z + 0.587f * G.z + 0.114f * Bc.z;
    o.w = 0.299f * R.w + 0.587f * G.w + 0.114f * Bc.w;
    ((float4*)gray)[g] = o;
}

// 2) LDS-tiled: sobel(replicate) + H 7-tap + V 7-tap gaussian + min-eig.
//    Tile = 64x16 outputs per 256-thread block.
__global__ __launch_bounds__(256) void k_front(const float* __restrict__ gray,
                                               float* __restrict__ S) {
    __shared__ float gt[24][72];
    __shared__ float pA[22][70], pC[22][70], pD[22][70];
    __shared__ float hA[22][64], hC[22][64], hD[22][64];
    int x0 = blockIdx.x * 64;
    int y0 = blockIdx.y * 16;
    int b = blockIdx.z;
    const float* gb = gray + (size_t)b * HWP;
    int tid = threadIdx.x;

    for (int idx = tid; idx < 24 * 72; idx += 256) {
        int r = idx / 72, c = idx % 72;
        int gy = min(max(y0 - 4 + r, 0), HH - 1);
        int gx = min(max(x0 - 4 + c, 0), WW - 1);
        gt[r][c] = gb[gy * WW + gx];
    }
    __syncthreads();

    for (int idx = tid; idx < 22 * 70; idx += 256) {
        int r = idx / 70, c = idx % 70;
        int py = y0 - 3 + r, px = x0 - 3 + c;
        if (py >= 0 && py < HH && px >= 0 && px < WW) {
            float g00 = gt[r][c],   g01 = gt[r][c+1],   g02 = gt[r][c+2];
            float g10 = gt[r+1][c],                     g12 = gt[r+1][c+2];
            float g20 = gt[r+2][c], g21 = gt[r+2][c+1], g22 = gt[r+2][c+2];
            float dx = (g02 - g00 + 2.f * (g12 - g10) + g22 - g20) * 0.125f;
            float dy = (g20 - g00 + 2.f * (g21 - g01) + g22 - g02) * 0.125f;
            pA[r][c] = dx * dx; pC[r][c] = dy * dy; pD[r][c] = dx * dy;
        }
    }
    __syncthreads();

    for (int idx = tid; idx < 22 * 64; idx += 256) {
        int r = idx / 64, c = idx % 64;
        int py = y0 - 3 + r;
        if (py >= 0 && py < HH) {
            int ox = x0 + c;
            float A = 0.f, C = 0.f, D = 0.f;
#pragma unroll
            for (int t = 0; t < 7; ++t) {
                int px = reflect_idx(ox - 3 + t, WW);
                int lc = px - (x0 - 3);
                float w = G7c[t];
                A += w * pA[r][lc]; C += w * pC[r][lc]; D += w * pD[r][lc];
            }
            hA[r][c] = A; hC[r][c] = C; hD[r][c] = D;
        }
    }
    __syncthreads();

    for (int idx = tid; idx < 16 * 64; idx += 256) {
        int r = idx / 64, c = idx % 64;
        int oy = y0 + r;
        float A = 0.f, C = 0.f, D = 0.f;
#pragma unroll
        for (int t = 0; t < 7; ++t) {
            int py = reflect_idx(oy - 3 + t, HH);
            int lr = py - (y0 - 3);
            float w = G7c[t];
            A += w * hA[lr][c]; C += w * hC[lr][c]; D += w * hD[lr][c];
        }
        float det = A * C - D * D;
        float tr = A + C;
        S[(size_t)b * HWP + (size_t)oy * WW + x0 + c] =
            0.5f * (tr - sqrtf(fabsf(tr * tr - 4.f * det)));
    }
}

// 3) per-wave 12x12 S tile in LDS -> 5x5 NMS + per-8x8-tile max -> slot
__global__ void k_cand2(const float* __restrict__ S, float* __restrict__ sval,
                        int* __restrict__ sidx, int* __restrict__ ocnt) {
    __shared__ float tile[4][12][12];
    int wave = threadIdx.x >> 6, lane = threadIdx.x & 63;
    int tx = blockIdx.x * 4 + wave;
    int ty = blockIdx.y;
    int b = blockIdx.z;
    const float* sb = S + (size_t)b * HWP;
    for (int t = lane; t < 144; t += 64) {
        int r = t / 12, c = t % 12;
        int yy = min(max(ty * 8 - 2 + r, 0), HH - 1);
        int xx = min(max(tx * 8 - 2 + c, 0), WW - 1);
        tile[wave][r][c] = sb[yy * WW + xx];
    }
    __syncthreads();
    int ly = lane >> 3, lx = lane & 7;
    float v = tile[wave][ly + 2][lx + 2];
    float m = -INFINITY;
#pragma unroll
    for (int dy = 0; dy < 5; ++dy)
#pragma unroll
        for (int dx = 0; dx < 5; ++dx)
            m = fmaxf(m, tile[wave][ly + dy][lx + dx]);
    float cval = (v == m) ? v : 0.f;
    int y = ty * 8 + ly, x = tx * 8 + lx;
    float tm = cval;
#pragma unroll
    for (int off = 32; off; off >>= 1)
        tm = fmaxf(tm, __shfl_xor(tm, off));
    unsigned long long mask = __ballot(cval == tm && cval > 0.f);
    int slot = ty * 64 + tx;
    if (mask) {
        int first = __ffsll(mask) - 1;
        if (lane == first) {
            sval[b * NKEY + slot] = cval;
            sidx[b * NKEY + slot] = y * WW + x;
        } else if ((mask >> lane) & 1ull) {
            int pos = atomicAdd(&ocnt[b], 1);
            if (pos < OCAP) {
                sval[b * NKEY + NSLOT + pos] = cval;
                sidx[b * NKEY + NSLOT + pos] = y * WW + x;
            }
        }
    } else if (lane == 0) {
        sval[b * NKEY + slot] = 0.f;
        sidx[b * NKEY + slot] = 0;
    }
}

// 4) exact 500th-largest 64-bit key per image via atomic-free MSB bit-descent
__global__ __launch_bounds__(256) void k_sel(const float* __restrict__ sval,
                       const int* __restrict__ sidx, const int* __restrict__ ocnt,
                       unsigned long long* __restrict__ selK) {
    __shared__ int shw[4];
    __shared__ int shtot;
    int b = blockIdx.x;
    int n = NSLOT + min(ocnt[b], OCAP);
    unsigned long long keys[NKPT];
    int cnt = 0;
#pragma unroll
    for (int t = 0; t < NKPT; ++t) {
        int i = threadIdx.x + t * 256;
        unsigned long long k = 0ull;
        if (i < n) {
            float v = sval[b * NKEY + i];
            if (v > 0.f) {
                unsigned int ix = (unsigned int)sidx[b * NKEY + i];
                k = ((unsigned long long)__float_as_uint(v) << 32) |
                    (unsigned long long)(~ix);
                cnt++;
            }
        }
        keys[t] = k;
    }
    int wid = threadIdx.x >> 6;
    {
        int c = cnt;
#pragma unroll
        for (int off = 32; off; off >>= 1) c += __shfl_down(c, off);
        if ((threadIdx.x & 63) == 0) shw[wid] = c;
        __syncthreads();
        if (threadIdx.x == 0) shtot = shw[0] + shw[1] + shw[2] + shw[3];
        __syncthreads();
    }
    int target = min(NCORN, shtot);
    unsigned long long T = 0ull;
    for (int bit = 63; bit >= 0; --bit) {
        unsigned long long cand = T | (1ull << bit);
        int c = 0;
#pragma unroll
        for (int t = 0; t < NKPT; ++t) c += (keys[t] >= cand) ? 1 : 0;
#pragma unroll
        for (int off = 32; off; off >>= 1) c += __shfl_down(c, off);
        __syncthreads();
        if ((threadIdx.x & 63) == 0) shw[wid] = c;
        __syncthreads();
        int tot = shw[0] + shw[1] + shw[2] + shw[3];
        if (tot >= target) T = cand;
    }
    if (threadIdx.x == 0) selK[b] = T;
}

// 5) sparse second NMS + BCE correction term C = sum_c w*(logp - log1mp).
//    No dense corners image. All threads reach the block reduction.
__global__ __launch_bounds__(256) void k_post(const float* __restrict__ sval,
                       const int* __restrict__ sidx, const int* __restrict__ ocnt,
                       const unsigned long long* __restrict__ selK,
                       const float* __restrict__ scores,
                       float* __restrict__ partialC) {
    int gid = blockIdx.x * 256 + threadIdx.x;
    int b = gid / NKEY, s = gid - b * NKEY;
    int novf = min(ocnt[b], OCAP);
    float contrib = 0.f;
    float v = (s < NSLOT + novf) ? sval[gid] : 0.f;
    if (v > 0.f) {
        unsigned int ix = (unsigned int)sidx[gid];
        unsigned long long K = selK[b];
        unsigned long long k = ((unsigned long long)__float_as_uint(v) << 32) |
                               (unsigned long long)(~ix);
        if (k >= K) {
            int y = (int)(ix >> 9), x = (int)(ix & 511);
            const float* bsv = sval + b * NKEY;
            const int* bsi = sidx + b * NKEY;
            bool sup = false;
            int ty0 = max(y - 2, 0) >> 3, ty1 = min(y + 2, HH - 1) >> 3;
            int tx0 = max(x - 2, 0) >> 3, tx1 = min(x + 2, WW - 1) >> 3;
            for (int ty = ty0; ty <= ty1 && !sup; ++ty)
                for (int tx = tx0; tx <= tx1 && !sup; ++tx) {
                    int s2 = ty * 64 + tx;
                    float v2 = bsv[s2];
                    if (v2 <= v) continue;
                    int ix2 = bsi[s2];
                    unsigned long long k2 = ((unsigned long long)__float_as_uint(v2) << 32) |
                                            (unsigned long long)(~(unsigned int)ix2);
                    if (k2 < K) continue;
                    int y2 = ix2 >> 9, x2 = ix2 & 511;
                    if (abs(y2 - y) <= 2 && abs(x2 - x) <= 2) sup = true;
                }
            for (int j = 0; j < novf && !sup; ++j) {
                float v2 = bsv[NSLOT + j];
                if (v2 <= v) continue;
                int ix2 = bsi[NSLOT + j];
                unsigned long long k2 = ((unsigned long long)__float_as_uint(v2) << 32) |
                                        (unsigned long long)(~(unsigned int)ix2);
                if (k2 < K) continue;
                int y2 = ix2 >> 9, x2 = ix2 & 511;
                if (abs(y2 - y) <= 2 && abs(x2 - x) <= 2) sup = true;
            }
            if (!sup) {
                const float* sb = scores + (size_t)b * HWP;
                if (y >= 3 && y <= HH - 4 && x >= 3 && x <= WW - 4) {
#pragma unroll
                    for (int j = -3; j <= 3; ++j) {
                        float wy = G7c[j + 3];
#pragma unroll
                        for (int i = -3; i <= 3; ++i) {
                            float w = wy * G7c[i + 3];
                            float p = sb[(y + j) * WW + (x + i)];
                            float lp = fmaxf(__logf(p), -100.f);
                            float l1p = fmaxf(__logf(1.f - p), -100.f);
                            contrib += w * (lp - l1p);
                        }
                    }
                } else {
                    int oy0 = max(y - 6, 0), oy1 = min(y + 6, HH - 1);
                    int ox0 = max(x - 6, 0), ox1 = min(x + 6, WW - 1);
                    for (int oy = oy0; oy <= oy1; ++oy) {
                        float wy = w1d(y, oy, HH);
                        if (wy == 0.f) continue;
                        for (int ox = ox0; ox <= ox1; ++ox) {
                            float wx = w1d(x, ox, WW);
                            if (wx == 0.f) continue;
                            float p = sb[oy * WW + ox];
                            float lp = fmaxf(__logf(p), -100.f);
                            float l1p = fmaxf(__logf(1.f - p), -100.f);
                            contrib += wy * wx * (lp - l1p);
                        }
                    }
                }
            }
        }
    }
#pragma unroll
    for (int off = 32; off; off >>= 1) contrib += __shfl_down(contrib, off);
    __shared__ float wsum[4];
    int wid = threadIdx.x >> 6;
    if ((threadIdx.x & 63) == 0) wsum[wid] = contrib;
    __syncthreads();
    if (threadIdx.x == 0)
        partialC[blockIdx.x] = wsum[0] + wsum[1] + wsum[2] + wsum[3];
}

// 6) streaming loss over scores only: A = sum(-clamped log1mp), B = sum p*exp(-lap)
__global__ __launch_bounds__(256) void k_loss(const float* __restrict__ scores,
                                              float* __restrict__ partial) {
    __shared__ float st[8][520];
    __shared__ float h5[8][512];
    int b = blockIdx.x >> 7;
    int rg = blockIdx.x & 127;
    int y0 = rg * 4;
    const float* sb = scores + (size_t)b * HWP;
    int tid = threadIdx.x;
    for (int idx = tid; idx < 8 * 516; idx += 256) {
        int i = idx / 516, c = idx % 516;
        int gy = reflect_idx(y0 - 2 + i, HH);
        int gx = reflect_idx(c - 2, WW);
        st[i][c] = sb[gy * WW + gx];
    }
    __syncthreads();
    for (int idx = tid; idx < 8 * 512; idx += 256) {
        int i = idx >> 9, x = idx & 511;
        h5[i][x] = st[i][x] + st[i][x + 1] + st[i][x + 2] + st[i][x + 3] + st[i][x + 4];
    }
    __syncthreads();
    float a_loc = 0.f, b_loc = 0.f;
#pragma unroll
    for (int k = 0; k < 8; ++k) {
        int idx = tid + k * 256;
        int r = idx >> 9, x = idx & 511;
        float p = st[r + 2][x + 2];
        float s25 = h5[r][x] + h5[r + 1][x] + h5[r + 2][x] + h5[r + 3][x] + h5[r + 4][x];
        float l1p = fmaxf(__logf(1.f - p), -100.f);
        a_loc -= l1p;
        float lap = (s25 - 25.f * p) * (1.0f / 48.0f);
        b_loc += p * __expf(-lap);
    }
#pragma unroll
    for (int off = 32; off; off >>= 1) {
        a_loc += __shfl_down(a_loc, off);
        b_loc += __shfl_down(b_loc, off);
    }
    __shared__ float wa[4], wbs[4];
    int wid = threadIdx.x >> 6;
    if ((threadIdx.x & 63) == 0) { wa[wid] = a_loc; wbs[wid] = b_loc; }
    __syncthreads();
    if (threadIdx.x == 0) {
        partial[blockIdx.x] = wa[0] + wa[1] + wa[2] + wa[3];
        partial[NBL + blockIdx.x] = wbs[0] + wbs[1] + wbs[2] + wbs[3];
    }
}

// 7) reduce partials -> scalar: out = (A - C)/N + 10*B/N
__global__ void k_reduce(const float* __restrict__ partial, float* __restrict__ out) {
    float ta = 0.f, tb = 0.f, tc = 0.f;
    for (int i = threadIdx.x; i < NBL; i += blockDim.x) {
        ta += partial[i];
        tb += partial[NBL + i];
    }
    for (int i = threadIdx.x; i < NPOSTB; i += blockDim.x)
        tc += partial[2 * NBL + i];
#pragma unroll
    for (int off = 32; off; off >>= 1) {
        ta += __shfl_down(ta, off);
        tb += __shfl_down(tb, off);
        tc += __shfl_down(tc, off);
    }
    __shared__ float wa[4], wb[4], wc[4];
    int wid = threadIdx.x >> 6, lid = threadIdx.x & 63;
    if (lid == 0) { wa[wid] = ta; wb[wid] = tb; wc[wid] = tc; }
    __syncthreads();
    if (threadIdx.x == 0) {
        float A = wa[0] + wa[1] + wa[2] + wa[3];
        float Bv = wb[0] + wb[1] + wb[2] + wb[3];
        float C = wc[0] + wc[1] + wc[2] + wc[3];
        float invN = 1.0f / (float)NPIX;
        out[0] = (A - C) * invN + 10.0f * Bv * invN;
    }
}

extern "C" void kernel_launch(void* const* d_in, const int* in_sizes, int n_in,
                              void* d_out, int out_size, void* d_ws, size_t ws_size,
                              hipStream_t stream) {
    const float* scores = (const float*)d_in[0];
    const float* imgs   = (const float*)d_in[1];
    float* out = (float*)d_out;

    float* ws = (float*)d_ws;
    float* A0 = ws;                     // gray
    float* A1 = ws + (size_t)NPIX;      // S
    float* sval = ws + 2 * (size_t)NPIX;              // [BB][NKEY]
    int*   sidx = (int*)(sval + (size_t)BB * NKEY);
    int*   ocnt = (int*)(sidx + (size_t)BB * NKEY);   // [BB]
    unsigned long long* selK = (unsigned long long*)(ocnt + BB);  // [BB]
    float* partial = (float*)(selK + BB);             // [2*NBL + NPOSTB]

    const int T = 256;
    const int GG = NG / T;              // 4096

    k_gray <<<GG, T, 0, stream>>>(imgs, A0);
    k_front<<<dim3(8, 32, BB), T, 0, stream>>>(A0, A1);

    hipMemsetAsync(ocnt, 0, BB * sizeof(int), stream);
    dim3 gcand(16, 64, BB);
    k_cand2<<<gcand, 256, 0, stream>>>(A1, sval, sidx, ocnt);

    k_sel<<<BB, 256, 0, stream>>>(sval, sidx, ocnt, selK);
    k_post<<<NPOSTB, 256, 0, stream>>>(sval, sidx, ocnt, selK, scores,
                                       partial + 2 * NBL);
    k_loss<<<NBL, T, 0, stream>>>(scores, partial);
    k_reduce<<<1, 256, 0, stream>>>(partial, out);
}